// Round 3
// baseline (726.417 us; speedup 1.0000x reference)
//
#include <hip/hip_runtime.h>
#include <cstdint>
#include <cstddef>

// Problem constants
#define NB    8
#define HWSZ  16384          // 128*128 positions per image
#define DIM   256
#define NCH   128            // s-chunks for attn partial sums (CHSZ = 128)
#define CHSZ  (HWSZ / NCH)

typedef short bf16x8 __attribute__((ext_vector_type(8)));
typedef float f32x4 __attribute__((ext_vector_type(4)));
typedef unsigned short u16;
typedef u16 u16x8 __attribute__((ext_vector_type(8)));

__device__ __forceinline__ float bf2f(u16 u) {
    union { uint32_t i; float f; } w; w.i = ((uint32_t)u) << 16; return w.f;
}
__device__ __forceinline__ u16 f2bf(float f) {
    union { float f; uint32_t i; } w; w.f = f;
    uint32_t x = w.i;
    return (u16)((x + 0x7fffu + ((x >> 16) & 1u)) >> 16);   // RNE
}

// async global -> LDS, 16 bytes per lane
__device__ __forceinline__ void gload_lds16(const u16* g, u16* l) {
    __builtin_amdgcn_global_load_lds(
        (const __attribute__((address_space(1))) uint32_t*)g,
        (__attribute__((address_space(3))) uint32_t*)l, 16, 0, 0);
}

// ---------------------------------------------------------------------------
// Convert + transpose a (K x N) f32 matrix into (N x K) bf16
__global__ void transpose_w32(const float* __restrict__ in, u16* __restrict__ out,
                              int K, int N) {
    int t = blockIdx.x * 256 + threadIdx.x;
    if (t < K * N) {
        int kk = t / N;
        int n  = t % N;
        out[(size_t)n * K + kk] = f2bf(in[t]);
    }
}

// Vectorized f32 -> bf16 elementwise convert (8 elems/thread)
__global__ void conv_bf16(const float* __restrict__ in, u16* __restrict__ out,
                          int n8) {
    int t = blockIdx.x * 256 + threadIdx.x;
    if (t < n8) {
        const float4* p = (const float4*)(in + (size_t)t * 8);
        float4 a = p[0], b = p[1];
        u16x8 o;
        o[0] = f2bf(a.x); o[1] = f2bf(a.y); o[2] = f2bf(a.z); o[3] = f2bf(a.w);
        o[4] = f2bf(b.x); o[5] = f2bf(b.y); o[6] = f2bf(b.z); o[7] = f2bf(b.w);
        *(u16x8*)(out + (size_t)t * 8) = o;
    }
}

// ---------------------------------------------------------------------------
// m97-structure GEMM: C[M,N] = A[M,K=256](bf16) * Bt[N,K](bf16)
// 128x128 block tile, 4 waves (2x2), each wave 64x64 via 4x4 16x16x32 MFMA
// fragments. BK=32, global_load_lds width-16 staging, 2 barriers/K-step.
#define GEMM_BODY(STORE_STMT)                                                   \
    __shared__ u16 At[128 * 32];                                                \
    __shared__ u16 Bl[128 * 32];                                                \
    const int t    = threadIdx.x;                                               \
    const int lane = t & 63;                                                    \
    const int wave = t >> 6;                                                    \
    const int r16  = lane & 15;                                                 \
    const int quad = lane >> 4;                                                 \
    const int m0   = blockIdx.y * 128;                                          \
    const int n0   = blockIdx.x * 128;                                          \
    const int K    = 256;                                                       \
    const int wm   = (wave >> 1) * 64;                                          \
    const int wn   = (wave & 1) * 64;                                           \
    f32x4 acc[4][4];                                                            \
    _Pragma("unroll")                                                           \
    for (int mi = 0; mi < 4; ++mi)                                              \
        _Pragma("unroll")                                                       \
        for (int ni = 0; ni < 4; ++ni)                                          \
            acc[mi][ni] = (f32x4){0.f, 0.f, 0.f, 0.f};                          \
    const int srow = t >> 2;            /* staging row 0..63 (+64 per it) */    \
    const int skc  = (t & 3) * 8;       /* staging k offset */                  \
    for (int kk = 0; kk < K; kk += 32) {                                        \
        if (kk) __syncthreads();                                                \
        _Pragma("unroll")                                                       \
        for (int it = 0; it < 2; ++it) {                                        \
            int c   = t + it * 256;                                             \
            int row = srow + it * 64;                                           \
            gload_lds16(A  + (size_t)(m0 + row) * K + kk + skc, At + c * 8);    \
            gload_lds16(Bt + (size_t)(n0 + row) * K + kk + skc, Bl + c * 8);    \
        }                                                                       \
        __syncthreads();                                                        \
        bf16x8 af[4], bfr[4];                                                   \
        _Pragma("unroll")                                                       \
        for (int mi = 0; mi < 4; ++mi)                                          \
            af[mi] = *(const bf16x8*)(At + (wm + mi * 16 + r16) * 32 + quad * 8);\
        _Pragma("unroll")                                                       \
        for (int ni = 0; ni < 4; ++ni)                                          \
            bfr[ni] = *(const bf16x8*)(Bl + (wn + ni * 16 + r16) * 32 + quad * 8);\
        _Pragma("unroll")                                                       \
        for (int mi = 0; mi < 4; ++mi)                                          \
            _Pragma("unroll")                                                   \
            for (int ni = 0; ni < 4; ++ni)                                      \
                acc[mi][ni] = __builtin_amdgcn_mfma_f32_16x16x32_bf16(          \
                    af[mi], bfr[ni], acc[mi][ni], 0, 0, 0);                     \
    }                                                                           \
    _Pragma("unroll")                                                           \
    for (int mi = 0; mi < 4; ++mi)                                              \
        _Pragma("unroll")                                                       \
        for (int ni = 0; ni < 4; ++ni)                                          \
            _Pragma("unroll")                                                   \
            for (int r = 0; r < 4; ++r) {                                       \
                int m = m0 + wm + mi * 16 + quad * 4 + r;                       \
                int n = n0 + wn + ni * 16 + r16;                                \
                STORE_STMT;                                                     \
            }

__global__ __launch_bounds__(256) void gemm_lds_cbf(const u16* __restrict__ A,
                                                    const u16* __restrict__ Bt,
                                                    u16* __restrict__ C, int N) {
    GEMM_BODY(C[(size_t)m * N + n] = f2bf(acc[mi][ni][r]))
}

__global__ __launch_bounds__(256) void gemm_lds_cf32(const u16* __restrict__ A,
                                                     const u16* __restrict__ Bt,
                                                     float* __restrict__ C, int N) {
    GEMM_BODY(C[(size_t)m * N + n] = acc[mi][ni][r])
}

// ---------------------------------------------------------------------------
// Depthwise 3x3 conv (SAME, zero pad) on qkv (CB,128,128,768) bf16, weights
// f32, + split + per-position normalization of q and k (stats f32).
// Branchless taps: all 9 loads issued back-to-back (ILP hides latency);
// OOB taps load the (valid) center address and are zeroed via cndmask.
__global__ __launch_bounds__(192) void dwconv_norm(
        const u16* __restrict__ qkv, const float* __restrict__ wdw,
        const float* __restrict__ mq, const float* __restrict__ vq,
        const float* __restrict__ mk, const float* __restrict__ vk,
        u16* __restrict__ qo, u16* __restrict__ ko, u16* __restrict__ vo) {
    int t  = blockIdx.x * 192 + threadIdx.x;
    int g  = t % 96;                // channel group (8 channels each)
    int p  = t / 96;                // position within chunk
    int c0 = g * 8;
    int b  = p >> 14;               // image within chunk
    int s  = p & 16383;
    int y  = s >> 7;
    int x  = s & 127;

    const u16* ctr = qkv + ((size_t)b * HWSZ + y * 128 + x) * 768 + c0;

    // 1) issue all 9 tap loads unconditionally (clamped to center when OOB)
    u16x8 tap[9];
#pragma unroll
    for (int kt = 0; kt < 9; ++kt) {
        const int dy = kt / 3 - 1;
        const int dx = kt % 3 - 1;
        const int off = (dy * 128 + dx) * 768;
        bool ok = ((unsigned)(y + dy) < 128u) & ((unsigned)(x + dx) < 128u);
        tap[kt] = *(const u16x8*)(ctr + (ok ? off : 0));
    }
    // 2) zero the invalid taps
    const u16x8 vzero = {0, 0, 0, 0, 0, 0, 0, 0};
#pragma unroll
    for (int kt = 0; kt < 9; ++kt) {
        const int dy = kt / 3 - 1;
        const int dx = kt % 3 - 1;
        bool ok = ((unsigned)(y + dy) < 128u) & ((unsigned)(x + dx) < 128u);
        if (!ok) tap[kt] = vzero;
    }

    // 3) accumulate
    float acc[8];
#pragma unroll
    for (int i = 0; i < 8; ++i) acc[i] = 0.f;
#pragma unroll
    for (int kt = 0; kt < 9; ++kt) {
        const float* wp = wdw + (size_t)kt * 768 + c0;
        float4 w0 = *(const float4*)wp;
        float4 w1 = *(const float4*)(wp + 4);
        const u16x8 in = tap[kt];
        acc[0] += bf2f(in[0]) * w0.x; acc[1] += bf2f(in[1]) * w0.y;
        acc[2] += bf2f(in[2]) * w0.z; acc[3] += bf2f(in[3]) * w0.w;
        acc[4] += bf2f(in[4]) * w1.x; acc[5] += bf2f(in[5]) * w1.y;
        acc[6] += bf2f(in[6]) * w1.z; acc[7] += bf2f(in[7]) * w1.w;
    }

    int seg = c0 >> 8;       // 0=q, 1=k, 2=v
    int cc  = c0 & 255;
    size_t op = (size_t)p * 256 + cc;
    u16x8 o;
    if (seg == 0) {
        float m = mq[s];
        float r = rsqrtf(vq[s]);
#pragma unroll
        for (int i = 0; i < 8; ++i) o[i] = f2bf((acc[i] - m) * r);
        *(u16x8*)(qo + op) = o;
    } else if (seg == 1) {
        float m = mk[s];
        float r = rsqrtf(vk[s]);
#pragma unroll
        for (int i = 0; i < 8; ++i) o[i] = f2bf((acc[i] - m) * r);
        *(u16x8*)(ko + op) = o;
    } else {
#pragma unroll
        for (int i = 0; i < 8; ++i) o[i] = f2bf(acc[i]);
        *(u16x8*)(vo + op) = o;
    }
}

// ---------------------------------------------------------------------------
// MFMA logits: attn_ps[ch][b*16+h][i*16+j] = sum_{s in chunk ch} k[b,s,16h+i]*q[b,s,16h+j]
__global__ __launch_bounds__(256) void attn_mfma(
        const u16* __restrict__ q, const u16* __restrict__ k,
        float* __restrict__ attn_ps, int nbn) {
    __shared__ u16 qt[32 * 256];
    __shared__ u16 kt[32 * 256];
    const int b    = blockIdx.x;           // image within chunk batch
    const int ch   = blockIdx.y;           // s-chunk
    const int t    = threadIdx.x;
    const int wave = t >> 6;
    const int lane = t & 63;
    const int r16  = lane & 15;
    const int quad = lane >> 4;
    const size_t base = (size_t)b * HWSZ * 256;
    const int sBeg = ch * CHSZ;

    f32x4 acc[4];
#pragma unroll
    for (int i = 0; i < 4; ++i) acc[i] = (f32x4){0.f, 0.f, 0.f, 0.f};

    for (int s0 = sBeg; s0 < sBeg + CHSZ; s0 += 32) {
        __syncthreads();
        // stage 32 rows x 256 ch of q and k; swizzle: pcol = col ^ ((row>>3)<<4)
#pragma unroll
        for (int r = 0; r < 4; ++r) {
            int c   = t + r * 256;
            int row = c >> 5;              // 0..31
            int c32 = c & 31;              // 16B chunk within row
            int pcol = (c32 * 8) ^ ((row >> 3) << 4);
            *(u16x8*)(&qt[row * 256 + pcol]) =
                *(const u16x8*)(q + base + (size_t)(s0 + row) * 256 + c32 * 8);
            *(u16x8*)(&kt[row * 256 + pcol]) =
                *(const u16x8*)(k + base + (size_t)(s0 + row) * 256 + c32 * 8);
        }
        __syncthreads();
#pragma unroll
        for (int h4 = 0; h4 < 4; ++h4) {
            int h   = wave * 4 + h4;
            int pc  = (h * 16 + r16) ^ (quad << 4);   // swizzled read col
            u16x8 ak, aq;
#pragma unroll
            for (int e = 0; e < 8; ++e) {
                int addr = (quad * 8 + e) * 256 + pc;
                ak[e] = kt[addr];
                aq[e] = qt[addr];
            }
            acc[h4] = __builtin_amdgcn_mfma_f32_16x16x32_bf16(
                (bf16x8)ak, (bf16x8)aq, acc[h4], 0, 0, 0);
        }
    }

#pragma unroll
    for (int h4 = 0; h4 < 4; ++h4) {
        int h  = wave * 4 + h4;
        int bn = b * 16 + h;
#pragma unroll
        for (int r = 0; r < 4; ++r) {
            attn_ps[((size_t)ch * nbn + bn) * 256 + (quad * 4 + r) * 16 + r16] =
                acc[h4][r];
        }
    }
}

// Sum NCH partial logit buffers -> attn_raw
__global__ void reduce_attn(const float* __restrict__ ps,
                            float* __restrict__ out, int n) {
    int t = blockIdx.x * 256 + threadIdx.x;
    if (t < n) {
        float s = 0.f;
        for (int c = 0; c < NCH; ++c) s += ps[(size_t)c * n + t];
        out[t] = s;
    }
}

// temperature * logits, softmax over axis i (per (bn,j) column)
__global__ __launch_bounds__(64) void softmax_attn(
        const float* __restrict__ attn, const float* __restrict__ temp,
        float* __restrict__ attn_sm) {
    int bn = blockIdx.x;
    int j  = threadIdx.x;
    if (j >= 16) return;
    float tj = temp[j];
    float vals[16];
    float mx = -3.4e38f;
#pragma unroll
    for (int i = 0; i < 16; ++i) {
        vals[i] = attn[bn * 256 + i * 16 + j] * tj;
        mx = fmaxf(mx, vals[i]);
    }
    float sum = 0.f;
#pragma unroll
    for (int i = 0; i < 16; ++i) {
        vals[i] = expf(vals[i] - mx);
        sum += vals[i];
    }
    float inv = 1.f / sum;
#pragma unroll
    for (int i = 0; i < 16; ++i)
        attn_sm[bn * 256 + i * 16 + j] = vals[i] * inv;
}

// out_mid[p, 16n+j] = sum_d v[p, 16n+d] * attn_sm[b,n,d,j]
__global__ __launch_bounds__(256) void apply_attn(
        const u16* __restrict__ v, const float* __restrict__ attn_sm,
        u16* __restrict__ out_mid) {
    __shared__ float alds[16 * 257];    // [head][256] padded
    const int tid = threadIdx.x;
    const int t   = blockIdx.x * 256 + tid;
    const int n   = t & 15;
    const int p   = t >> 4;
    const int b   = p >> 14;

    // stage this image's 16 head matrices into LDS
#pragma unroll
    for (int r = 0; r < 16; ++r) {
        int idx = r * 256 + tid;
        alds[(idx >> 8) * 257 + (idx & 255)] = attn_sm[(size_t)b * 4096 + idx];
    }
    __syncthreads();

    const u16* vp = v + (size_t)p * 256 + n * 16;
    u16x8 v0 = *(const u16x8*)vp;
    u16x8 v1 = *(const u16x8*)(vp + 8);
    float vv[16];
#pragma unroll
    for (int i = 0; i < 8; ++i) { vv[i] = bf2f(v0[i]); vv[8 + i] = bf2f(v1[i]); }

    const float* am = &alds[n * 257];
    float o[16];
#pragma unroll
    for (int j = 0; j < 16; ++j) o[j] = 0.f;
#pragma unroll
    for (int d = 0; d < 16; ++d) {
        float vd = vv[d];
#pragma unroll
        for (int j = 0; j < 16; ++j) o[j] += vd * am[d * 16 + j];
    }

    u16x8 o0, o1;
#pragma unroll
    for (int i = 0; i < 8; ++i) { o0[i] = f2bf(o[i]); o1[i] = f2bf(o[8 + i]); }
    u16* outp = out_mid + (size_t)p * 256 + n * 16;
    *(u16x8*)outp       = o0;
    *(u16x8*)(outp + 8) = o1;
}

// ---------------------------------------------------------------------------
extern "C" void kernel_launch(void* const* d_in, const int* in_sizes, int n_in,
                              void* d_out, int out_size, void* d_ws, size_t ws_size,
                              hipStream_t stream) {
    const float* x     = (const float*)d_in[0];   // (8,128,128,256) f32
    const float* wqkv  = (const float*)d_in[1];   // (256,768) f32
    const float* wdw   = (const float*)d_in[2];   // (3,3,1,768) f32
    const float* wout  = (const float*)d_in[3];   // (256,256) f32
    const float* temp  = (const float*)d_in[4];   // (16,) f32
    const float* mq    = (const float*)d_in[5];   // (16384,) f32
    const float* vq    = (const float*)d_in[6];
    const float* mk    = (const float*)d_in[7];
    const float* vk    = (const float*)d_in[8];
    float* out_f = (float*)d_out;                  // f32 output! (ref is f32)

    // Fixed-size workspace pieces
    char* ws = (char*)d_ws;
    u16*   btq      = (u16*)ws;                              // 768x256 bf16
    u16*   bto      = (u16*)(ws + 768 * 256 * 2);            // 256x256 bf16
    char*  dynb     = ws + 768 * 256 * 2 + 256 * 256 * 2;
    const size_t FIXED = (size_t)(768 * 256 * 2 + 256 * 256 * 2);

    const size_t PER_IMG = (size_t)HWSZ * 768 * 2 + 3 * (size_t)HWSZ * 256 * 2
                         + 2 * 4096 * 4;
    int CB = 8;
    while (CB > 1 && FIXED + (size_t)CB * PER_IMG > ws_size) CB >>= 1;

    transpose_w32<<<(256 * 768 + 255) / 256, 256, 0, stream>>>(wqkv, btq, 256, 768);
    transpose_w32<<<(256 * 256 + 255) / 256, 256, 0, stream>>>(wout, bto, 256, 256);

    const size_t QKVB = (size_t)CB * HWSZ * 768 * 2;
    const size_t SEGB = (size_t)CB * HWSZ * 256 * 2;
    u16*   qkv_c    = (u16*)dynb;
    u16*   qb       = (u16*)(dynb + QKVB);
    u16*   kb       = (u16*)(dynb + QKVB + SEGB);
    u16*   vb       = (u16*)(dynb + QKVB + 2 * SEGB);
    float* attn_raw = (float*)(dynb + QKVB + 3 * SEGB);
    float* attn_sm  = attn_raw + (size_t)CB * 4096;
    u16*   om_c     = qkv_c;                 // reuse (dead after dwconv)
    u16*   xb       = qb;                    // x-bf16 staging (dead before dwconv writes qb)
    float* attn_ps  = (float*)qkv_c;         // partial logits (qkv dead after dwconv)

    const int rowsC = CB * HWSZ;
    const int nbn   = CB * 16;
    for (int b0 = 0; b0 < NB; b0 += CB) {
        const float* xc   = x + (size_t)b0 * HWSZ * 256;
        float*       outc = out_f + (size_t)b0 * HWSZ * 256;

        // 0. x -> bf16
        conv_bf16<<<(rowsC * 32 + 255) / 256, 256, 0, stream>>>(xc, xb, rowsC * 32);

        // 1. qkv = x @ w_qkv    (rowsC x 256 x 768), 128^2-tile LDS GEMM
        gemm_lds_cbf<<<dim3(768 / 128, rowsC / 128), 256, 0, stream>>>(xb, btq,
                                                                       qkv_c, 768);
        // 2. depthwise 3x3 + normalization + split (qkv dead after this)
        dwconv_norm<<<(rowsC * 96) / 192, 192, 0, stream>>>(qkv_c, wdw,
                                                            mq, vq, mk, vk,
                                                            qb, kb, vb);
        // 3. logits partials (MFMA) + reduce + temperature/softmax
        attn_mfma<<<dim3(CB, NCH), 256, 0, stream>>>(qb, kb, attn_ps, nbn);
        reduce_attn<<<(CB * 4096 + 255) / 256, 256, 0, stream>>>(attn_ps, attn_raw,
                                                                 CB * 4096);
        softmax_attn<<<CB * 16, 64, 0, stream>>>(attn_raw, temp, attn_sm);

        // 4. out_mid = v @ attn  (attn_ps dead; om_c reuses the same region)
        apply_attn<<<(rowsC * 16) / 256, 256, 0, stream>>>(vb, attn_sm, om_c);

        // 5. out = out_mid @ w_out   (rowsC x 256 x 256), f32 output
        gemm_lds_cf32<<<dim3(256 / 128, rowsC / 128), 256, 0, stream>>>(om_c, bto,
                                                                        outc, 256);
    }
}

// Round 4
// 631.694 us; speedup vs baseline: 1.1500x; 1.1500x over previous
//
#include <hip/hip_runtime.h>
#include <cstdint>
#include <cstddef>

// Problem constants
#define NB    8
#define HWSZ  16384          // 128*128 positions per image
#define DIM   256
#define NCH   128            // s-chunks for attn partial sums (CHSZ = 128)
#define CHSZ  (HWSZ / NCH)

typedef short bf16x8 __attribute__((ext_vector_type(8)));
typedef float f32x4 __attribute__((ext_vector_type(4)));
typedef unsigned short u16;
typedef u16 u16x8 __attribute__((ext_vector_type(8)));

__device__ __forceinline__ float bf2f(u16 u) {
    union { uint32_t i; float f; } w; w.i = ((uint32_t)u) << 16; return w.f;
}
__device__ __forceinline__ u16 f2bf(float f) {
    union { float f; uint32_t i; } w; w.f = f;
    uint32_t x = w.i;
    return (u16)((x + 0x7fffu + ((x >> 16) & 1u)) >> 16);   // RNE
}

// async global -> LDS, 16 bytes per lane
__device__ __forceinline__ void gload_lds16(const u16* g, u16* l) {
    __builtin_amdgcn_global_load_lds(
        (const __attribute__((address_space(1))) uint32_t*)g,
        (__attribute__((address_space(3))) uint32_t*)l, 16, 0, 0);
}

// ---------------------------------------------------------------------------
// Convert + transpose a (K x N) f32 matrix into (N x K) bf16
__global__ void transpose_w32(const float* __restrict__ in, u16* __restrict__ out,
                              int K, int N) {
    int t = blockIdx.x * 256 + threadIdx.x;
    if (t < K * N) {
        int kk = t / N;
        int n  = t % N;
        out[(size_t)n * K + kk] = f2bf(in[t]);
    }
}

// Vectorized f32 -> bf16 elementwise convert (8 elems/thread)
__global__ void conv_bf16(const float* __restrict__ in, u16* __restrict__ out,
                          int n8) {
    int t = blockIdx.x * 256 + threadIdx.x;
    if (t < n8) {
        const float4* p = (const float4*)(in + (size_t)t * 8);
        float4 a = p[0], b = p[1];
        u16x8 o;
        o[0] = f2bf(a.x); o[1] = f2bf(a.y); o[2] = f2bf(a.z); o[3] = f2bf(a.w);
        o[4] = f2bf(b.x); o[5] = f2bf(b.y); o[6] = f2bf(b.z); o[7] = f2bf(b.w);
        *(u16x8*)(out + (size_t)t * 8) = o;
    }
}

// ---------------------------------------------------------------------------
// m97-structure GEMM: C[M,N] = A[M,K=256](bf16) * Bt[N,K](bf16)
// 128x128 block tile, 4 waves (2x2), each wave 64x64 via 4x4 16x16x32 MFMA
// fragments. BK=32, global_load_lds width-16 staging, 2 barriers/K-step.
#define GEMM_BODY(STORE_STMT)                                                   \
    __shared__ u16 At[128 * 32];                                                \
    __shared__ u16 Bl[128 * 32];                                                \
    const int t    = threadIdx.x;                                               \
    const int lane = t & 63;                                                    \
    const int wave = t >> 6;                                                    \
    const int r16  = lane & 15;                                                 \
    const int quad = lane >> 4;                                                 \
    const int m0   = blockIdx.y * 128;                                          \
    const int n0   = blockIdx.x * 128;                                          \
    const int K    = 256;                                                       \
    const int wm   = (wave >> 1) * 64;                                          \
    const int wn   = (wave & 1) * 64;                                           \
    f32x4 acc[4][4];                                                            \
    _Pragma("unroll")                                                           \
    for (int mi = 0; mi < 4; ++mi)                                              \
        _Pragma("unroll")                                                       \
        for (int ni = 0; ni < 4; ++ni)                                          \
            acc[mi][ni] = (f32x4){0.f, 0.f, 0.f, 0.f};                          \
    const int srow = t >> 2;            /* staging row 0..63 (+64 per it) */    \
    const int skc  = (t & 3) * 8;       /* staging k offset */                  \
    for (int kk = 0; kk < K; kk += 32) {                                        \
        if (kk) __syncthreads();                                                \
        _Pragma("unroll")                                                       \
        for (int it = 0; it < 2; ++it) {                                        \
            int c   = t + it * 256;                                             \
            int row = srow + it * 64;                                           \
            gload_lds16(A  + (size_t)(m0 + row) * K + kk + skc, At + c * 8);    \
            gload_lds16(Bt + (size_t)(n0 + row) * K + kk + skc, Bl + c * 8);    \
        }                                                                       \
        __syncthreads();                                                        \
        bf16x8 af[4], bfr[4];                                                   \
        _Pragma("unroll")                                                       \
        for (int mi = 0; mi < 4; ++mi)                                          \
            af[mi] = *(const bf16x8*)(At + (wm + mi * 16 + r16) * 32 + quad * 8);\
        _Pragma("unroll")                                                       \
        for (int ni = 0; ni < 4; ++ni)                                          \
            bfr[ni] = *(const bf16x8*)(Bl + (wn + ni * 16 + r16) * 32 + quad * 8);\
        _Pragma("unroll")                                                       \
        for (int mi = 0; mi < 4; ++mi)                                          \
            _Pragma("unroll")                                                   \
            for (int ni = 0; ni < 4; ++ni)                                      \
                acc[mi][ni] = __builtin_amdgcn_mfma_f32_16x16x32_bf16(          \
                    af[mi], bfr[ni], acc[mi][ni], 0, 0, 0);                     \
    }                                                                           \
    _Pragma("unroll")                                                           \
    for (int mi = 0; mi < 4; ++mi)                                              \
        _Pragma("unroll")                                                       \
        for (int ni = 0; ni < 4; ++ni)                                          \
            _Pragma("unroll")                                                   \
            for (int r = 0; r < 4; ++r) {                                       \
                int m = m0 + wm + mi * 16 + quad * 4 + r;                       \
                int n = n0 + wn + ni * 16 + r16;                                \
                STORE_STMT;                                                     \
            }

__global__ __launch_bounds__(256) void gemm_lds_cbf(const u16* __restrict__ A,
                                                    const u16* __restrict__ Bt,
                                                    u16* __restrict__ C, int N) {
    GEMM_BODY(C[(size_t)m * N + n] = f2bf(acc[mi][ni][r]))
}

__global__ __launch_bounds__(256) void gemm_lds_cf32(const u16* __restrict__ A,
                                                     const u16* __restrict__ Bt,
                                                     float* __restrict__ C, int N) {
    GEMM_BODY(C[(size_t)m * N + n] = acc[mi][ni][r])
}

// ---------------------------------------------------------------------------
// Depthwise 3x3 conv (SAME, zero pad) + split + q/k normalization.
// v3: each thread owns (8-ch slab, column x, 4 vertical outputs). Sliding
// 6-row window: 18 tap loads + 18 weight loads per 4 outputs (9 VMEM/output
// vs 27 in v2). Rows clamped to valid addresses, zeroed via cndmask.
// Block 192 = 96 slabs x 2 x-columns -> contiguous 3KB spans per tap row.
__global__ __launch_bounds__(192, 2) void dwconv_norm(
        const u16* __restrict__ qkv, const float* __restrict__ wdw,
        const float* __restrict__ mq, const float* __restrict__ vq,
        const float* __restrict__ mk, const float* __restrict__ vk,
        u16* __restrict__ qo, u16* __restrict__ ko, u16* __restrict__ vo) {
    const int t    = threadIdx.x;
    const int g    = t % 96;               // channel slab (8 ch)
    const int c0   = g * 8;
    const int xcol = t / 96;               // 0/1
    const int x    = blockIdx.x * 2 + xcol;
    const int y0   = blockIdx.y * 4;
    const int b    = blockIdx.z;

    // weights: 9 taps x 8 ch, loaded once per thread (amortized over 4 outputs)
    float w[9][8];
#pragma unroll
    for (int kt = 0; kt < 9; ++kt) {
        float4 w0 = *(const float4*)(wdw + (size_t)kt * 768 + c0);
        float4 w1 = *(const float4*)(wdw + (size_t)kt * 768 + c0 + 4);
        w[kt][0] = w0.x; w[kt][1] = w0.y; w[kt][2] = w0.z; w[kt][3] = w0.w;
        w[kt][4] = w1.x; w[kt][5] = w1.y; w[kt][6] = w1.z; w[kt][7] = w1.w;
    }

    float acc[4][8];
#pragma unroll
    for (int r = 0; r < 4; ++r)
#pragma unroll
        for (int c = 0; c < 8; ++c) acc[r][c] = 0.f;

    const bool xlok = (x > 0);
    const bool xrok = (x < 127);
    const u16x8 vz = {0, 0, 0, 0, 0, 0, 0, 0};

#pragma unroll
    for (int i = 0; i < 6; ++i) {          // input rows y0-1 .. y0+4
        const int  rowy = y0 - 1 + i;
        const bool rok  = (unsigned)rowy < 128u;
        const int  rowc = rowy < 0 ? 0 : (rowy > 127 ? 127 : rowy);
        const u16* rp = qkv + ((size_t)b * HWSZ + rowc * 128 + x) * 768 + c0;
        // x-1/x+1 at image edge read adjacent (mapped) workspace bytes, then
        // get zeroed below — never dereferences unmapped memory.
        u16x8 a0 = *(const u16x8*)(rp - 768);
        u16x8 a1 = *(const u16x8*)(rp);
        u16x8 a2 = *(const u16x8*)(rp + 768);
        if (!(rok && xlok)) a0 = vz;
        if (!rok)           a1 = vz;
        if (!(rok && xrok)) a2 = vz;
        float f0[8], f1[8], f2[8];
#pragma unroll
        for (int c = 0; c < 8; ++c) {
            f0[c] = bf2f(a0[c]); f1[c] = bf2f(a1[c]); f2[c] = bf2f(a2[c]);
        }
#pragma unroll
        for (int r = 0; r < 4; ++r) {
            if (r < i - 2 || r > i) continue;   // compile-time pruned
            const int tr = (i - r) * 3;         // (dy+1)*3, dy = i-1-r
#pragma unroll
            for (int c = 0; c < 8; ++c) {
                acc[r][c] += f0[c] * w[tr + 0][c];
                acc[r][c] += f1[c] * w[tr + 1][c];
                acc[r][c] += f2[c] * w[tr + 2][c];
            }
        }
    }

    const int seg = c0 >> 8;       // 0=q, 1=k, 2=v
    const int cc  = c0 & 255;
#pragma unroll
    for (int r = 0; r < 4; ++r) {
        const int    s  = (y0 + r) * 128 + x;
        const size_t p  = (size_t)b * HWSZ + s;
        const size_t op = p * 256 + cc;
        u16x8 o;
        if (seg == 0) {
            float m = mq[s], rs = rsqrtf(vq[s]);
#pragma unroll
            for (int c = 0; c < 8; ++c) o[c] = f2bf((acc[r][c] - m) * rs);
            *(u16x8*)(qo + op) = o;
        } else if (seg == 1) {
            float m = mk[s], rs = rsqrtf(vk[s]);
#pragma unroll
            for (int c = 0; c < 8; ++c) o[c] = f2bf((acc[r][c] - m) * rs);
            *(u16x8*)(ko + op) = o;
        } else {
#pragma unroll
            for (int c = 0; c < 8; ++c) o[c] = f2bf(acc[r][c]);
            *(u16x8*)(vo + op) = o;
        }
    }
}

// ---------------------------------------------------------------------------
// MFMA logits: attn_ps[ch][b*16+h][i*16+j] = sum_{s in chunk ch} k[b,s,16h+i]*q[b,s,16h+j]
__global__ __launch_bounds__(256) void attn_mfma(
        const u16* __restrict__ q, const u16* __restrict__ k,
        float* __restrict__ attn_ps, int nbn) {
    __shared__ u16 qt[32 * 256];
    __shared__ u16 kt[32 * 256];
    const int b    = blockIdx.x;           // image within chunk batch
    const int ch   = blockIdx.y;           // s-chunk
    const int t    = threadIdx.x;
    const int wave = t >> 6;
    const int lane = t & 63;
    const int r16  = lane & 15;
    const int quad = lane >> 4;
    const size_t base = (size_t)b * HWSZ * 256;
    const int sBeg = ch * CHSZ;

    f32x4 acc[4];
#pragma unroll
    for (int i = 0; i < 4; ++i) acc[i] = (f32x4){0.f, 0.f, 0.f, 0.f};

    for (int s0 = sBeg; s0 < sBeg + CHSZ; s0 += 32) {
        __syncthreads();
        // stage 32 rows x 256 ch of q and k; swizzle: pcol = col ^ ((row>>3)<<4)
#pragma unroll
        for (int r = 0; r < 4; ++r) {
            int c   = t + r * 256;
            int row = c >> 5;              // 0..31
            int c32 = c & 31;              // 16B chunk within row
            int pcol = (c32 * 8) ^ ((row >> 3) << 4);
            *(u16x8*)(&qt[row * 256 + pcol]) =
                *(const u16x8*)(q + base + (size_t)(s0 + row) * 256 + c32 * 8);
            *(u16x8*)(&kt[row * 256 + pcol]) =
                *(const u16x8*)(k + base + (size_t)(s0 + row) * 256 + c32 * 8);
        }
        __syncthreads();
#pragma unroll
        for (int h4 = 0; h4 < 4; ++h4) {
            int h   = wave * 4 + h4;
            int pc  = (h * 16 + r16) ^ (quad << 4);   // swizzled read col
            u16x8 ak, aq;
#pragma unroll
            for (int e = 0; e < 8; ++e) {
                int addr = (quad * 8 + e) * 256 + pc;
                ak[e] = kt[addr];
                aq[e] = qt[addr];
            }
            acc[h4] = __builtin_amdgcn_mfma_f32_16x16x32_bf16(
                (bf16x8)ak, (bf16x8)aq, acc[h4], 0, 0, 0);
        }
    }

#pragma unroll
    for (int h4 = 0; h4 < 4; ++h4) {
        int h  = wave * 4 + h4;
        int bn = b * 16 + h;
#pragma unroll
        for (int r = 0; r < 4; ++r) {
            attn_ps[((size_t)ch * nbn + bn) * 256 + (quad * 4 + r) * 16 + r16] =
                acc[h4][r];
        }
    }
}

// Sum NCH partial logit buffers -> attn_raw
__global__ void reduce_attn(const float* __restrict__ ps,
                            float* __restrict__ out, int n) {
    int t = blockIdx.x * 256 + threadIdx.x;
    if (t < n) {
        float s = 0.f;
        for (int c = 0; c < NCH; ++c) s += ps[(size_t)c * n + t];
        out[t] = s;
    }
}

// temperature * logits, softmax over axis i (per (bn,j) column)
__global__ __launch_bounds__(64) void softmax_attn(
        const float* __restrict__ attn, const float* __restrict__ temp,
        float* __restrict__ attn_sm) {
    int bn = blockIdx.x;
    int j  = threadIdx.x;
    if (j >= 16) return;
    float tj = temp[j];
    float vals[16];
    float mx = -3.4e38f;
#pragma unroll
    for (int i = 0; i < 16; ++i) {
        vals[i] = attn[bn * 256 + i * 16 + j] * tj;
        mx = fmaxf(mx, vals[i]);
    }
    float sum = 0.f;
#pragma unroll
    for (int i = 0; i < 16; ++i) {
        vals[i] = expf(vals[i] - mx);
        sum += vals[i];
    }
    float inv = 1.f / sum;
#pragma unroll
    for (int i = 0; i < 16; ++i)
        attn_sm[bn * 256 + i * 16 + j] = vals[i] * inv;
}

// out_mid[p, 16n+j] = sum_d v[p, 16n+d] * attn_sm[b,n,d,j]
__global__ __launch_bounds__(256) void apply_attn(
        const u16* __restrict__ v, const float* __restrict__ attn_sm,
        u16* __restrict__ out_mid) {
    __shared__ float alds[16 * 257];    // [head][256] padded
    const int tid = threadIdx.x;
    const int t   = blockIdx.x * 256 + tid;
    const int n   = t & 15;
    const int p   = t >> 4;
    const int b   = p >> 14;

    // stage this image's 16 head matrices into LDS
#pragma unroll
    for (int r = 0; r < 16; ++r) {
        int idx = r * 256 + tid;
        alds[(idx >> 8) * 257 + (idx & 255)] = attn_sm[(size_t)b * 4096 + idx];
    }
    __syncthreads();

    const u16* vp = v + (size_t)p * 256 + n * 16;
    u16x8 v0 = *(const u16x8*)vp;
    u16x8 v1 = *(const u16x8*)(vp + 8);
    float vv[16];
#pragma unroll
    for (int i = 0; i < 8; ++i) { vv[i] = bf2f(v0[i]); vv[8 + i] = bf2f(v1[i]); }

    const float* am = &alds[n * 257];
    float o[16];
#pragma unroll
    for (int j = 0; j < 16; ++j) o[j] = 0.f;
#pragma unroll
    for (int d = 0; d < 16; ++d) {
        float vd = vv[d];
#pragma unroll
        for (int j = 0; j < 16; ++j) o[j] += vd * am[d * 16 + j];
    }

    u16x8 o0, o1;
#pragma unroll
    for (int i = 0; i < 8; ++i) { o0[i] = f2bf(o[i]); o1[i] = f2bf(o[8 + i]); }
    u16* outp = out_mid + (size_t)p * 256 + n * 16;
    *(u16x8*)outp       = o0;
    *(u16x8*)(outp + 8) = o1;
}

// ---------------------------------------------------------------------------
extern "C" void kernel_launch(void* const* d_in, const int* in_sizes, int n_in,
                              void* d_out, int out_size, void* d_ws, size_t ws_size,
                              hipStream_t stream) {
    const float* x     = (const float*)d_in[0];   // (8,128,128,256) f32
    const float* wqkv  = (const float*)d_in[1];   // (256,768) f32
    const float* wdw   = (const float*)d_in[2];   // (3,3,1,768) f32
    const float* wout  = (const float*)d_in[3];   // (256,256) f32
    const float* temp  = (const float*)d_in[4];   // (16,) f32
    const float* mq    = (const float*)d_in[5];   // (16384,) f32
    const float* vq    = (const float*)d_in[6];
    const float* mk    = (const float*)d_in[7];
    const float* vk    = (const float*)d_in[8];
    float* out_f = (float*)d_out;                  // f32 output! (ref is f32)

    // Fixed-size workspace pieces
    char* ws = (char*)d_ws;
    u16*   btq      = (u16*)ws;                              // 768x256 bf16
    u16*   bto      = (u16*)(ws + 768 * 256 * 2);            // 256x256 bf16
    char*  dynb     = ws + 768 * 256 * 2 + 256 * 256 * 2;
    const size_t FIXED = (size_t)(768 * 256 * 2 + 256 * 256 * 2);

    const size_t PER_IMG = (size_t)HWSZ * 768 * 2 + 3 * (size_t)HWSZ * 256 * 2
                         + 2 * 4096 * 4;
    int CB = 8;
    while (CB > 1 && FIXED + (size_t)CB * PER_IMG > ws_size) CB >>= 1;

    transpose_w32<<<(256 * 768 + 255) / 256, 256, 0, stream>>>(wqkv, btq, 256, 768);
    transpose_w32<<<(256 * 256 + 255) / 256, 256, 0, stream>>>(wout, bto, 256, 256);

    const size_t QKVB = (size_t)CB * HWSZ * 768 * 2;
    const size_t SEGB = (size_t)CB * HWSZ * 256 * 2;
    u16*   qkv_c    = (u16*)dynb;
    u16*   qb       = (u16*)(dynb + QKVB);
    u16*   kb       = (u16*)(dynb + QKVB + SEGB);
    u16*   vb       = (u16*)(dynb + QKVB + 2 * SEGB);
    float* attn_raw = (float*)(dynb + QKVB + 3 * SEGB);
    float* attn_sm  = attn_raw + (size_t)CB * 4096;
    u16*   om_c     = qkv_c;                 // reuse (dead after dwconv)
    u16*   xb       = qb;                    // x-bf16 staging (dead before dwconv writes qb)
    float* attn_ps  = (float*)qkv_c;         // partial logits (qkv dead after dwconv)

    const int rowsC = CB * HWSZ;
    const int nbn   = CB * 16;
    for (int b0 = 0; b0 < NB; b0 += CB) {
        const float* xc   = x + (size_t)b0 * HWSZ * 256;
        float*       outc = out_f + (size_t)b0 * HWSZ * 256;

        // 0. x -> bf16
        conv_bf16<<<(rowsC * 32 + 255) / 256, 256, 0, stream>>>(xc, xb, rowsC * 32);

        // 1. qkv = x @ w_qkv    (rowsC x 256 x 768), 128^2-tile LDS GEMM
        gemm_lds_cbf<<<dim3(768 / 128, rowsC / 128), 256, 0, stream>>>(xb, btq,
                                                                       qkv_c, 768);
        // 2. depthwise 3x3 + normalization + split (qkv dead after this)
        dwconv_norm<<<dim3(64, 32, CB), 192, 0, stream>>>(qkv_c, wdw,
                                                          mq, vq, mk, vk,
                                                          qb, kb, vb);
        // 3. logits partials (MFMA) + reduce + temperature/softmax
        attn_mfma<<<dim3(CB, NCH), 256, 0, stream>>>(qb, kb, attn_ps, nbn);
        reduce_attn<<<(CB * 4096 + 255) / 256, 256, 0, stream>>>(attn_ps, attn_raw,
                                                                 CB * 4096);
        softmax_attn<<<CB * 16, 64, 0, stream>>>(attn_raw, temp, attn_sm);

        // 4. out_mid = v @ attn  (attn_ps dead; om_c reuses the same region)
        apply_attn<<<(rowsC * 16) / 256, 256, 0, stream>>>(vb, attn_sm, om_c);

        // 5. out = out_mid @ w_out   (rowsC x 256 x 256), f32 output
        gemm_lds_cf32<<<dim3(256 / 128, rowsC / 128), 256, 0, stream>>>(om_c, bto,
                                                                        outc, 256);
    }
}

// Round 5
// 602.960 us; speedup vs baseline: 1.2048x; 1.0477x over previous
//
#include <hip/hip_runtime.h>
#include <cstdint>
#include <cstddef>

// Problem constants
#define NB    8
#define HWSZ  16384          // 128*128 positions per image
#define DIM   256
#define NCH   128            // s-chunks for attn partial sums (CHSZ = 128)
#define CHSZ  (HWSZ / NCH)

typedef short bf16x8 __attribute__((ext_vector_type(8)));
typedef float f32x4 __attribute__((ext_vector_type(4)));
typedef unsigned short u16;
typedef u16 u16x8 __attribute__((ext_vector_type(8)));

__device__ __forceinline__ float bf2f(u16 u) {
    union { uint32_t i; float f; } w; w.i = ((uint32_t)u) << 16; return w.f;
}
__device__ __forceinline__ u16 f2bf(float f) {
    union { float f; uint32_t i; } w; w.f = f;
    uint32_t x = w.i;
    return (u16)((x + 0x7fffu + ((x >> 16) & 1u)) >> 16);   // RNE
}

// async global -> LDS, 16 bytes per lane
__device__ __forceinline__ void gload_lds16(const u16* g, u16* l) {
    __builtin_amdgcn_global_load_lds(
        (const __attribute__((address_space(1))) uint32_t*)g,
        (__attribute__((address_space(3))) uint32_t*)l, 16, 0, 0);
}

// ---------------------------------------------------------------------------
// Convert + transpose a (K x N) f32 matrix into (N x K) bf16
__global__ void transpose_w32(const float* __restrict__ in, u16* __restrict__ out,
                              int K, int N) {
    int t = blockIdx.x * 256 + threadIdx.x;
    if (t < K * N) {
        int kk = t / N;
        int n  = t % N;
        out[(size_t)n * K + kk] = f2bf(in[t]);
    }
}

// Vectorized f32 -> bf16 elementwise convert (8 elems/thread)
__global__ void conv_bf16(const float* __restrict__ in, u16* __restrict__ out,
                          int n8) {
    int t = blockIdx.x * 256 + threadIdx.x;
    if (t < n8) {
        const float4* p = (const float4*)(in + (size_t)t * 8);
        float4 a = p[0], b = p[1];
        u16x8 o;
        o[0] = f2bf(a.x); o[1] = f2bf(a.y); o[2] = f2bf(a.z); o[3] = f2bf(a.w);
        o[4] = f2bf(b.x); o[5] = f2bf(b.y); o[6] = f2bf(b.z); o[7] = f2bf(b.w);
        *(u16x8*)(out + (size_t)t * 8) = o;
    }
}

// ---------------------------------------------------------------------------
// m97-structure GEMM: C[M,N] = A[M,K=256](bf16) * Bt[N,K](bf16)
// 128x128 block tile, 4 waves (2x2), each wave 64x64 via 4x4 16x16x32 MFMA
// fragments. BK=32, global_load_lds width-16 staging, 2 barriers/K-step.
// XCD-aware swizzle: nwg is always a multiple of 8 here; each XCD gets a
// contiguous chunk of y-panels so all n-blocks of a panel share one L2.
#define GEMM_BODY(STORE_STMT)                                                   \
    __shared__ u16 At[128 * 32];                                                \
    __shared__ u16 Bl[128 * 32];                                                \
    const int nwg = gridDim.x * gridDim.y;                                      \
    const int bid = blockIdx.y * gridDim.x + blockIdx.x;                        \
    const int swz = (bid & 7) * (nwg >> 3) + (bid >> 3);                        \
    const int bx  = swz % gridDim.x;                                            \
    const int by  = swz / gridDim.x;                                            \
    const int t    = threadIdx.x;                                               \
    const int lane = t & 63;                                                    \
    const int wave = t >> 6;                                                    \
    const int r16  = lane & 15;                                                 \
    const int quad = lane >> 4;                                                 \
    const int m0   = by * 128;                                                  \
    const int n0   = bx * 128;                                                  \
    const int K    = 256;                                                       \
    const int wm   = (wave >> 1) * 64;                                          \
    const int wn   = (wave & 1) * 64;                                           \
    f32x4 acc[4][4];                                                            \
    _Pragma("unroll")                                                           \
    for (int mi = 0; mi < 4; ++mi)                                              \
        _Pragma("unroll")                                                       \
        for (int ni = 0; ni < 4; ++ni)                                          \
            acc[mi][ni] = (f32x4){0.f, 0.f, 0.f, 0.f};                          \
    const int srow = t >> 2;            /* staging row 0..63 (+64 per it) */    \
    const int skc  = (t & 3) * 8;       /* staging k offset */                  \
    for (int kk = 0; kk < K; kk += 32) {                                        \
        if (kk) __syncthreads();                                                \
        _Pragma("unroll")                                                       \
        for (int it = 0; it < 2; ++it) {                                        \
            int c   = t + it * 256;                                             \
            int row = srow + it * 64;                                           \
            gload_lds16(A  + (size_t)(m0 + row) * K + kk + skc, At + c * 8);    \
            gload_lds16(Bt + (size_t)(n0 + row) * K + kk + skc, Bl + c * 8);    \
        }                                                                       \
        __syncthreads();                                                        \
        bf16x8 af[4], bfr[4];                                                   \
        _Pragma("unroll")                                                       \
        for (int mi = 0; mi < 4; ++mi)                                          \
            af[mi] = *(const bf16x8*)(At + (wm + mi * 16 + r16) * 32 + quad * 8);\
        _Pragma("unroll")                                                       \
        for (int ni = 0; ni < 4; ++ni)                                          \
            bfr[ni] = *(const bf16x8*)(Bl + (wn + ni * 16 + r16) * 32 + quad * 8);\
        _Pragma("unroll")                                                       \
        for (int mi = 0; mi < 4; ++mi)                                          \
            _Pragma("unroll")                                                   \
            for (int ni = 0; ni < 4; ++ni)                                      \
                acc[mi][ni] = __builtin_amdgcn_mfma_f32_16x16x32_bf16(          \
                    af[mi], bfr[ni], acc[mi][ni], 0, 0, 0);                     \
    }                                                                           \
    _Pragma("unroll")                                                           \
    for (int mi = 0; mi < 4; ++mi)                                              \
        _Pragma("unroll")                                                       \
        for (int ni = 0; ni < 4; ++ni)                                          \
            _Pragma("unroll")                                                   \
            for (int r = 0; r < 4; ++r) {                                       \
                int m = m0 + wm + mi * 16 + quad * 4 + r;                       \
                int n = n0 + wn + ni * 16 + r16;                                \
                STORE_STMT;                                                     \
            }

__global__ __launch_bounds__(256) void gemm_lds_cbf(const u16* __restrict__ A,
                                                    const u16* __restrict__ Bt,
                                                    u16* __restrict__ C, int N) {
    GEMM_BODY(C[(size_t)m * N + n] = f2bf(acc[mi][ni][r]))
}

__global__ __launch_bounds__(256) void gemm_lds_cf32(const u16* __restrict__ A,
                                                     const u16* __restrict__ Bt,
                                                     float* __restrict__ C, int N) {
    GEMM_BODY(C[(size_t)m * N + n] = acc[mi][ni][r])
}

// ---------------------------------------------------------------------------
// Depthwise 3x3 conv (SAME, zero pad) + split + q/k normalization.
// v4 = v3 structure, but WITHOUT the waves-per-eu hint: round-4 counters
// showed __launch_bounds__(192,2) capped residency at ~1.5 waves/EU
// (Occupancy 76% -> 19%); VGPR=92 permits ~5 waves/EU.
__global__ __launch_bounds__(192) void dwconv_norm(
        const u16* __restrict__ qkv, const float* __restrict__ wdw,
        const float* __restrict__ mq, const float* __restrict__ vq,
        const float* __restrict__ mk, const float* __restrict__ vk,
        u16* __restrict__ qo, u16* __restrict__ ko, u16* __restrict__ vo) {
    const int t    = threadIdx.x;
    const int g    = t % 96;               // channel slab (8 ch)
    const int c0   = g * 8;
    const int xcol = t / 96;               // 0/1
    const int x    = blockIdx.x * 2 + xcol;
    const int y0   = blockIdx.y * 4;
    const int b    = blockIdx.z;

    // weights: 9 taps x 8 ch, loaded once per thread (amortized over 4 outputs)
    float w[9][8];
#pragma unroll
    for (int kt = 0; kt < 9; ++kt) {
        float4 w0 = *(const float4*)(wdw + (size_t)kt * 768 + c0);
        float4 w1 = *(const float4*)(wdw + (size_t)kt * 768 + c0 + 4);
        w[kt][0] = w0.x; w[kt][1] = w0.y; w[kt][2] = w0.z; w[kt][3] = w0.w;
        w[kt][4] = w1.x; w[kt][5] = w1.y; w[kt][6] = w1.z; w[kt][7] = w1.w;
    }

    float acc[4][8];
#pragma unroll
    for (int r = 0; r < 4; ++r)
#pragma unroll
        for (int c = 0; c < 8; ++c) acc[r][c] = 0.f;

    const bool xlok = (x > 0);
    const bool xrok = (x < 127);
    const u16x8 vz = {0, 0, 0, 0, 0, 0, 0, 0};

#pragma unroll
    for (int i = 0; i < 6; ++i) {          // input rows y0-1 .. y0+4
        const int  rowy = y0 - 1 + i;
        const bool rok  = (unsigned)rowy < 128u;
        const int  rowc = rowy < 0 ? 0 : (rowy > 127 ? 127 : rowy);
        const u16* rp = qkv + ((size_t)b * HWSZ + rowc * 128 + x) * 768 + c0;
        // x-1/x+1 at image edge read adjacent (mapped) workspace bytes, then
        // get zeroed below — never dereferences unmapped memory.
        u16x8 a0 = *(const u16x8*)(rp - 768);
        u16x8 a1 = *(const u16x8*)(rp);
        u16x8 a2 = *(const u16x8*)(rp + 768);
        if (!(rok && xlok)) a0 = vz;
        if (!rok)           a1 = vz;
        if (!(rok && xrok)) a2 = vz;
        float f0[8], f1[8], f2[8];
#pragma unroll
        for (int c = 0; c < 8; ++c) {
            f0[c] = bf2f(a0[c]); f1[c] = bf2f(a1[c]); f2[c] = bf2f(a2[c]);
        }
#pragma unroll
        for (int r = 0; r < 4; ++r) {
            if (r < i - 2 || r > i) continue;   // compile-time pruned
            const int tr = (i - r) * 3;         // (dy+1)*3, dy = i-1-r
#pragma unroll
            for (int c = 0; c < 8; ++c) {
                acc[r][c] += f0[c] * w[tr + 0][c];
                acc[r][c] += f1[c] * w[tr + 1][c];
                acc[r][c] += f2[c] * w[tr + 2][c];
            }
        }
    }

    const int seg = c0 >> 8;       // 0=q, 1=k, 2=v
    const int cc  = c0 & 255;
#pragma unroll
    for (int r = 0; r < 4; ++r) {
        const int    s  = (y0 + r) * 128 + x;
        const size_t p  = (size_t)b * HWSZ + s;
        const size_t op = p * 256 + cc;
        u16x8 o;
        if (seg == 0) {
            float m = mq[s], rs = rsqrtf(vq[s]);
#pragma unroll
            for (int c = 0; c < 8; ++c) o[c] = f2bf((acc[r][c] - m) * rs);
            *(u16x8*)(qo + op) = o;
        } else if (seg == 1) {
            float m = mk[s], rs = rsqrtf(vk[s]);
#pragma unroll
            for (int c = 0; c < 8; ++c) o[c] = f2bf((acc[r][c] - m) * rs);
            *(u16x8*)(ko + op) = o;
        } else {
#pragma unroll
            for (int c = 0; c < 8; ++c) o[c] = f2bf(acc[r][c]);
            *(u16x8*)(vo + op) = o;
        }
    }
}

// ---------------------------------------------------------------------------
// MFMA logits: attn_ps[ch][b*16+h][i*16+j] = sum_{s in chunk ch} k[b,s,16h+i]*q[b,s,16h+j]
__global__ __launch_bounds__(256) void attn_mfma(
        const u16* __restrict__ q, const u16* __restrict__ k,
        float* __restrict__ attn_ps, int nbn) {
    __shared__ u16 qt[32 * 256];
    __shared__ u16 kt[32 * 256];
    const int b    = blockIdx.x;           // image within chunk batch
    const int ch   = blockIdx.y;           // s-chunk
    const int t    = threadIdx.x;
    const int wave = t >> 6;
    const int lane = t & 63;
    const int r16  = lane & 15;
    const int quad = lane >> 4;
    const size_t base = (size_t)b * HWSZ * 256;
    const int sBeg = ch * CHSZ;

    f32x4 acc[4];
#pragma unroll
    for (int i = 0; i < 4; ++i) acc[i] = (f32x4){0.f, 0.f, 0.f, 0.f};

    for (int s0 = sBeg; s0 < sBeg + CHSZ; s0 += 32) {
        __syncthreads();
        // stage 32 rows x 256 ch of q and k; swizzle: pcol = col ^ ((row>>3)<<4)
#pragma unroll
        for (int r = 0; r < 4; ++r) {
            int c   = t + r * 256;
            int row = c >> 5;              // 0..31
            int c32 = c & 31;              // 16B chunk within row
            int pcol = (c32 * 8) ^ ((row >> 3) << 4);
            *(u16x8*)(&qt[row * 256 + pcol]) =
                *(const u16x8*)(q + base + (size_t)(s0 + row) * 256 + c32 * 8);
            *(u16x8*)(&kt[row * 256 + pcol]) =
                *(const u16x8*)(k + base + (size_t)(s0 + row) * 256 + c32 * 8);
        }
        __syncthreads();
#pragma unroll
        for (int h4 = 0; h4 < 4; ++h4) {
            int h   = wave * 4 + h4;
            int pc  = (h * 16 + r16) ^ (quad << 4);   // swizzled read col
            u16x8 ak, aq;
#pragma unroll
            for (int e = 0; e < 8; ++e) {
                int addr = (quad * 8 + e) * 256 + pc;
                ak[e] = kt[addr];
                aq[e] = qt[addr];
            }
            acc[h4] = __builtin_amdgcn_mfma_f32_16x16x32_bf16(
                (bf16x8)ak, (bf16x8)aq, acc[h4], 0, 0, 0);
        }
    }

#pragma unroll
    for (int h4 = 0; h4 < 4; ++h4) {
        int h  = wave * 4 + h4;
        int bn = b * 16 + h;
#pragma unroll
        for (int r = 0; r < 4; ++r) {
            attn_ps[((size_t)ch * nbn + bn) * 256 + (quad * 4 + r) * 16 + r16] =
                acc[h4][r];
        }
    }
}

// Sum NCH partial logit buffers -> attn_raw
__global__ void reduce_attn(const float* __restrict__ ps,
                            float* __restrict__ out, int n) {
    int t = blockIdx.x * 256 + threadIdx.x;
    if (t < n) {
        float s = 0.f;
        for (int c = 0; c < NCH; ++c) s += ps[(size_t)c * n + t];
        out[t] = s;
    }
}

// temperature * logits, softmax over axis i (per (bn,j) column)
__global__ __launch_bounds__(64) void softmax_attn(
        const float* __restrict__ attn, const float* __restrict__ temp,
        float* __restrict__ attn_sm) {
    int bn = blockIdx.x;
    int j  = threadIdx.x;
    if (j >= 16) return;
    float tj = temp[j];
    float vals[16];
    float mx = -3.4e38f;
#pragma unroll
    for (int i = 0; i < 16; ++i) {
        vals[i] = attn[bn * 256 + i * 16 + j] * tj;
        mx = fmaxf(mx, vals[i]);
    }
    float sum = 0.f;
#pragma unroll
    for (int i = 0; i < 16; ++i) {
        vals[i] = expf(vals[i] - mx);
        sum += vals[i];
    }
    float inv = 1.f / sum;
#pragma unroll
    for (int i = 0; i < 16; ++i)
        attn_sm[bn * 256 + i * 16 + j] = vals[i] * inv;
}

// out_mid[p, 16n+j] = sum_d v[p, 16n+d] * attn_sm[b,n,d,j]
__global__ __launch_bounds__(256) void apply_attn(
        const u16* __restrict__ v, const float* __restrict__ attn_sm,
        u16* __restrict__ out_mid) {
    __shared__ float alds[16 * 257];    // [head][256] padded
    const int tid = threadIdx.x;
    const int t   = blockIdx.x * 256 + tid;
    const int n   = t & 15;
    const int p   = t >> 4;
    const int b   = p >> 14;

    // stage this image's 16 head matrices into LDS
#pragma unroll
    for (int r = 0; r < 16; ++r) {
        int idx = r * 256 + tid;
        alds[(idx >> 8) * 257 + (idx & 255)] = attn_sm[(size_t)b * 4096 + idx];
    }
    __syncthreads();

    const u16* vp = v + (size_t)p * 256 + n * 16;
    u16x8 v0 = *(const u16x8*)vp;
    u16x8 v1 = *(const u16x8*)(vp + 8);
    float vv[16];
#pragma unroll
    for (int i = 0; i < 8; ++i) { vv[i] = bf2f(v0[i]); vv[8 + i] = bf2f(v1[i]); }

    const float* am = &alds[n * 257];
    float o[16];
#pragma unroll
    for (int j = 0; j < 16; ++j) o[j] = 0.f;
#pragma unroll
    for (int d = 0; d < 16; ++d) {
        float vd = vv[d];
#pragma unroll
        for (int j = 0; j < 16; ++j) o[j] += vd * am[d * 16 + j];
    }

    u16x8 o0, o1;
#pragma unroll
    for (int i = 0; i < 8; ++i) { o0[i] = f2bf(o[i]); o1[i] = f2bf(o[8 + i]); }
    u16* outp = out_mid + (size_t)p * 256 + n * 16;
    *(u16x8*)outp       = o0;
    *(u16x8*)(outp + 8) = o1;
}

// ---------------------------------------------------------------------------
extern "C" void kernel_launch(void* const* d_in, const int* in_sizes, int n_in,
                              void* d_out, int out_size, void* d_ws, size_t ws_size,
                              hipStream_t stream) {
    const float* x     = (const float*)d_in[0];   // (8,128,128,256) f32
    const float* wqkv  = (const float*)d_in[1];   // (256,768) f32
    const float* wdw   = (const float*)d_in[2];   // (3,3,1,768) f32
    const float* wout  = (const float*)d_in[3];   // (256,256) f32
    const float* temp  = (const float*)d_in[4];   // (16,) f32
    const float* mq    = (const float*)d_in[5];   // (16384,) f32
    const float* vq    = (const float*)d_in[6];
    const float* mk    = (const float*)d_in[7];
    const float* vk    = (const float*)d_in[8];
    float* out_f = (float*)d_out;                  // f32 output! (ref is f32)

    // Fixed-size workspace pieces
    char* ws = (char*)d_ws;
    u16*   btq      = (u16*)ws;                              // 768x256 bf16
    u16*   bto      = (u16*)(ws + 768 * 256 * 2);            // 256x256 bf16
    char*  dynb     = ws + 768 * 256 * 2 + 256 * 256 * 2;
    const size_t FIXED = (size_t)(768 * 256 * 2 + 256 * 256 * 2);

    const size_t PER_IMG = (size_t)HWSZ * 768 * 2 + 3 * (size_t)HWSZ * 256 * 2
                         + 2 * 4096 * 4;
    int CB = 8;
    while (CB > 1 && FIXED + (size_t)CB * PER_IMG > ws_size) CB >>= 1;

    transpose_w32<<<(256 * 768 + 255) / 256, 256, 0, stream>>>(wqkv, btq, 256, 768);
    transpose_w32<<<(256 * 256 + 255) / 256, 256, 0, stream>>>(wout, bto, 256, 256);

    const size_t QKVB = (size_t)CB * HWSZ * 768 * 2;
    const size_t SEGB = (size_t)CB * HWSZ * 256 * 2;
    u16*   qkv_c    = (u16*)dynb;
    u16*   qb       = (u16*)(dynb + QKVB);
    u16*   kb       = (u16*)(dynb + QKVB + SEGB);
    u16*   vb       = (u16*)(dynb + QKVB + 2 * SEGB);
    float* attn_raw = (float*)(dynb + QKVB + 3 * SEGB);
    float* attn_sm  = attn_raw + (size_t)CB * 4096;
    u16*   om_c     = qkv_c;                 // reuse (dead after dwconv)
    u16*   xb       = qb;                    // x-bf16 staging (dead before dwconv writes qb)
    float* attn_ps  = (float*)qkv_c;         // partial logits (qkv dead after dwconv)

    const int rowsC = CB * HWSZ;
    const int nbn   = CB * 16;
    for (int b0 = 0; b0 < NB; b0 += CB) {
        const float* xc   = x + (size_t)b0 * HWSZ * 256;
        float*       outc = out_f + (size_t)b0 * HWSZ * 256;

        // 0. x -> bf16
        conv_bf16<<<(rowsC * 32 + 255) / 256, 256, 0, stream>>>(xc, xb, rowsC * 32);

        // 1. qkv = x @ w_qkv    (rowsC x 256 x 768), 128^2-tile LDS GEMM
        gemm_lds_cbf<<<dim3(768 / 128, rowsC / 128), 256, 0, stream>>>(xb, btq,
                                                                       qkv_c, 768);
        // 2. depthwise 3x3 + normalization + split (qkv dead after this)
        dwconv_norm<<<dim3(64, 32, CB), 192, 0, stream>>>(qkv_c, wdw,
                                                          mq, vq, mk, vk,
                                                          qb, kb, vb);
        // 3. logits partials (MFMA) + reduce + temperature/softmax
        attn_mfma<<<dim3(CB, NCH), 256, 0, stream>>>(qb, kb, attn_ps, nbn);
        reduce_attn<<<(CB * 4096 + 255) / 256, 256, 0, stream>>>(attn_ps, attn_raw,
                                                                 CB * 4096);
        softmax_attn<<<CB * 16, 64, 0, stream>>>(attn_raw, temp, attn_sm);

        // 4. out_mid = v @ attn  (attn_ps dead; om_c reuses the same region)
        apply_attn<<<(rowsC * 16) / 256, 256, 0, stream>>>(vb, attn_sm, om_c);

        // 5. out = out_mid @ w_out   (rowsC x 256 x 256), f32 output
        gemm_lds_cf32<<<dim3(256 / 128, rowsC / 128), 256, 0, stream>>>(om_c, bto,
                                                                        outc, 256);
    }
}